// Round 1
// 240.050 us; speedup vs baseline: 1.0899x; 1.0899x over previous
//
#include <hip/hip_runtime.h>
#include <hip/hip_bf16.h>

typedef unsigned short u16;
typedef unsigned int   u32;
typedef __attribute__((ext_vector_type(8))) short bf16x8;
typedef __attribute__((ext_vector_type(4))) float f32x4;

#define EPSV 1e-5f

// Established (R1-R10): all float inputs fp32, idx int32-or-int64, output fp32.
// ws planes bf16/u32-packed (absmax 0.0078 << 0.0273 threshold).
__device__ __forceinline__ float b2f(u16 u) {
    union { u32 i; float f; } x; x.i = ((u32)u) << 16; return x.f;
}
__device__ __forceinline__ u16 f2b(float f) {
    union { float f; u32 i; } x; x.f = f;
    u32 lsb = (x.i >> 16) & 1u;
    return (u16)((x.i + 0x7fffu + lsb) >> 16);
}
__device__ __forceinline__ bf16x8 pack8(float4 a, float4 b) {
    bf16x8 r;
    r[0] = (short)f2b(a.x); r[1] = (short)f2b(a.y);
    r[2] = (short)f2b(a.z); r[3] = (short)f2b(a.w);
    r[4] = (short)f2b(b.x); r[5] = (short)f2b(b.y);
    r[6] = (short)f2b(b.z); r[7] = (short)f2b(b.w);
    return r;
}
__device__ __forceinline__ float rdlane_f(float v, int lane) {
    return __uint_as_float(__builtin_amdgcn_readlane(__float_as_uint(v), lane));
}

// ---------------- Kernel 1: q/k/v projection, LDS-staged MFMA GEMM (R10-proven) ----
__global__ __launch_bounds__(256) void kvq_mfma(
    const float* __restrict__ x,
    const float* __restrict__ Wq, const float* __restrict__ bq,
    const float* __restrict__ Wk, const float* __restrict__ bk,
    const float* __restrict__ Wv, const float* __restrict__ bv,
    u16* __restrict__ qb, u32* __restrict__ kvb,
    int N)
{
    __shared__ u16 Wl[3 * 64 * 72];
    __shared__ u16 xl[64 * 72];
    const int t = threadIdx.x;

    const float* Wg[3] = {Wq, Wk, Wv};
#pragma unroll
    for (int mat = 0; mat < 3; ++mat) {
        const float4* Wsrc = (const float4*)Wg[mat];
#pragma unroll
        for (int it = 0; it < 4; ++it) {
            int id4 = t + it * 256;
            int row = id4 >> 4;
            int c4  = id4 & 15;
            float4 f = Wsrc[id4];
            u32 lo = (u32)f2b(f.x) | ((u32)f2b(f.y) << 16);
            u32 hi = (u32)f2b(f.z) | ((u32)f2b(f.w) << 16);
            u32* d = (u32*)&Wl[(mat * 64 + row) * 72 + c4 * 4];
            d[0] = lo; d[1] = hi;
        }
    }
    int base = blockIdx.x * 64;
#pragma unroll
    for (int it = 0; it < 4; ++it) {
        int id4 = t + it * 256;
        int row = id4 >> 4;
        int c4  = id4 & 15;
        int gi = base + row; if (gi >= N) gi = N - 1;
        float4 f = ((const float4*)(x + (size_t)gi * 64))[c4];
        u32 lo = (u32)f2b(f.x) | ((u32)f2b(f.y) << 16);
        u32 hi = (u32)f2b(f.z) | ((u32)f2b(f.w) << 16);
        u32* d = (u32*)&xl[row * 72 + c4 * 4];
        d[0] = lo; d[1] = hi;
    }
    __syncthreads();

    const int lane = t & 63;
    const int wid  = t >> 6;
    const int n_   = lane & 15;
    const int quad = lane >> 4;

    bf16x8 a0 = *(const bf16x8*)&xl[(wid * 16 + n_) * 72 + quad * 8];
    bf16x8 a1 = *(const bf16x8*)&xl[(wid * 16 + n_) * 72 + 32 + quad * 8];

    f32x4 acc[12];
#pragma unroll
    for (int nt = 0; nt < 12; ++nt) {
        int mat = nt >> 2;
        int c = ((nt & 3) << 4) + n_;
        bf16x8 b0 = *(const bf16x8*)&Wl[(mat * 64 + c) * 72 + quad * 8];
        bf16x8 b1 = *(const bf16x8*)&Wl[(mat * 64 + c) * 72 + 32 + quad * 8];
        f32x4 z = {0.f, 0.f, 0.f, 0.f};
        z = __builtin_amdgcn_mfma_f32_16x16x32_bf16(a0, b0, z, 0, 0, 0);
        z = __builtin_amdgcn_mfma_f32_16x16x32_bf16(a1, b1, z, 0, 0, 0);
        acc[nt] = z;
    }

    int rbase = base + wid * 16 + quad * 4;
#pragma unroll
    for (int g4 = 0; g4 < 4; ++g4) {
        int c = (g4 << 4) + n_;
        float biasq = bq[c], biask = bk[c], biasv = bv[c];
#pragma unroll
        for (int r = 0; r < 4; ++r) {
            int i2 = rbase + r;
            if (i2 < N) {
                qb[(size_t)i2 * 64 + c] = f2b(acc[g4][r] + biasq);
                u32 kvp = (u32)f2b(acc[4 + g4][r] + biask)
                        | ((u32)f2b(acc[8 + g4][r] + biasv) << 16);
                kvb[(size_t)i2 * 64 + c] = kvp;
            }
        }
    }
}

// ---------------- Kernel 2: fused attention, MFMA score path ----------------
// R11: all LDS buffers are wave-private (wrT[wid]/hbnT[wid]/wT[wid]) -> the
// three __syncthreads() were pure inter-wave lockstep overhead (VALUBusy 71%,
// Occ 43% at only 56 VGPR). Replaced with same-wave s_waitcnt lgkmcnt(0).
// Broadcasts (nbr,u0,u1,u2) moved from ds_bpermute to v_readlane (SGPR), which
// also makes the kvb gather address scalar; 16 gather loads batched up front.
__global__ __launch_bounds__(256) void attn_mfma(
    const float* __restrict__ p, const int* __restrict__ idx32,
    const u16* __restrict__ qb, const u32* __restrict__ kvb,
    const float* __restrict__ pw1, const float* __restrict__ pb1,
    const float* __restrict__ g3, const float* __restrict__ b3,
    const float* __restrict__ m3, const float* __restrict__ v3,
    const float* __restrict__ pw2, const float* __restrict__ pb2,
    const float* __restrict__ g1, const float* __restrict__ b1,
    const float* __restrict__ m1, const float* __restrict__ v1,
    const float* __restrict__ ww1, const float* __restrict__ wb1,
    const float* __restrict__ g2, const float* __restrict__ b2c,
    const float* __restrict__ m2, const float* __restrict__ v2,
    const float* __restrict__ ww2, const float* __restrict__ wb2,
    float* __restrict__ out, int N)
{
    __shared__ u16   wrT[4][16 * 72];   // wr transpose, row stride 72 u16 (144B, b128-aligned)
    __shared__ u16   hbnT[4][16 * 16];  // hbn transpose, row stride 16 u16 (32B)
    __shared__ float wT[4][16 * 9];     // softmax weights, row stride 9 f32

    const int lane = threadIdx.x & 63;
    const int wid  = threadIdx.x >> 6;
    int i = blockIdx.x * 4 + wid;
    bool active = (i < N);
    int ic = active ? i : 0;
    const int m    = lane & 7;
    const int n16  = lane & 15;
    const int quad = lane >> 4;

    bool idx64 = (idx32[1] == 0) & (idx32[3] == 0) & (idx32[5] == 0) & (idx32[7] == 0);

    // ---- per-lane params ----
    float qc  = b2f(qb[(size_t)ic * 64 + lane]);
    float s1  = g1[lane] * rsqrtf(v1[lane] + EPSV);
    float bb1 = b1[lane] - m1[lane] * s1;
    float pw2_0 = pw2[lane * 3 + 0];
    float pw2_1 = pw2[lane * 3 + 1];
    float pw2_2 = pw2[lane * 3 + 2];
    float pb2c  = pb2[lane];
    float s2   = g2[m] * rsqrtf(v2[m] + EPSV);
    float bb2v = b2c[m] - m2[m] * s2;
    float wb1m = wb1[m];
    float wb2m = wb2[m];
    float pix = p[(size_t)ic * 3 + 0];
    float piy = p[(size_t)ic * 3 + 1];
    float piz = p[(size_t)ic * 3 + 2];

    // neighbor index for this lane's slot
    size_t ii = (size_t)ic * 16 + n16;
    int nbr = idx64 ? idx32[ii * 2] : idx32[ii];
    if ((unsigned)nbr >= (unsigned)N) nbr = 0;

    // ---- linear_p u-values once in lane j (j = lane&15) ----
    float u0l, u1l, u2l;
    {
        float pdx = p[(size_t)nbr * 3 + 0] - pix;
        float pdy = p[(size_t)nbr * 3 + 1] - piy;
        float pdz = p[(size_t)nbr * 3 + 2] - piz;
        float a0 = pw1[0] * pdx + pw1[1] * pdy + pw1[2] * pdz + pb1[0];
        float a1 = pw1[3] * pdx + pw1[4] * pdy + pw1[5] * pdz + pb1[1];
        float a2 = pw1[6] * pdx + pw1[7] * pdy + pw1[8] * pdz + pb1[2];
        float sa0 = g3[0] * rsqrtf(v3[0] + EPSV);
        float sa1 = g3[1] * rsqrtf(v3[1] + EPSV);
        float sa2 = g3[2] * rsqrtf(v3[2] + EPSV);
        u0l = fmaxf(0.f, a0 * sa0 + (b3[0] - m3[0] * sa0));
        u1l = fmaxf(0.f, a1 * sa1 + (b3[1] - m3[1] * sa1));
        u2l = fmaxf(0.f, a2 * sa2 + (b3[2] - m3[2] * sa2));
    }

    // ---- B fragment for h1 = wr (16x64) @ ww1^T (64x8): B[k=c][n] = ww1[n&7][c] ----
    bf16x8 b0, b1f;
    {
        const float4* r4 = (const float4*)(ww1 + (size_t)m * 64);  // (lane&15)&7 == lane&7
        b0  = pack8(r4[quad * 2 + 0], r4[quad * 2 + 1]);
        b1f = pack8(r4[8 + quad * 2 + 0], r4[8 + quad * 2 + 1]);
    }
    // ---- B fragment for h2 = hbn (16x8, K-padded) @ ww2^T: nonzero only quad 0 ----
    bf16x8 b2f_ = {};
    if (quad == 0) {
        const float4* r4 = (const float4*)(ww2 + (size_t)m * 8);
        b2f_ = pack8(r4[0], r4[1]);
    }

    // ---- batch the 16 kv gathers (scalar base addresses, all in flight) ----
    u32 kvw[16];
#pragma unroll
    for (int j = 0; j < 16; ++j) {
        int nj = __builtin_amdgcn_readlane(nbr, j);     // SGPR -> scalar addr math
        kvw[j] = kvb[(size_t)nj * 64 + lane];
    }

    // ---- per-neighbor: pr, wr -> LDS (A-transpose), vpr in regs ----
    float vpr[16];
    u16* myWr = wrT[wid];
#pragma unroll
    for (int j = 0; j < 16; ++j) {
        float u0 = rdlane_f(u0l, j);
        float u1 = rdlane_f(u1l, j);
        float u2 = rdlane_f(u2l, j);
        float pr = fmaf(u0, pw2_0, fmaf(u1, pw2_1, fmaf(u2, pw2_2, pb2c)));
        u32 w = kvw[j];
        float kc = __uint_as_float(w << 16);           // low  bf16 -> f32
        float vc = __uint_as_float(w & 0xffff0000u);   // high bf16 -> f32
        vpr[j] = vc + pr;
        float wr = fmaxf(0.f, (kc - qc + pr) * s1 + bb1);
        myWr[j * 72 + lane] = f2b(wr);
    }
    // same-wave LDS RAW only -> lgkmcnt drain, no block barrier
    asm volatile("s_waitcnt lgkmcnt(0)" ::: "memory");
    __builtin_amdgcn_sched_barrier(0);

    // ---- h1 MFMA: A row j=n16, k = quad*8.. / 32+quad*8.. ----
    bf16x8 a0 = *(const bf16x8*)&myWr[n16 * 72 + quad * 8];
    bf16x8 a1 = *(const bf16x8*)&myWr[n16 * 72 + 32 + quad * 8];
    f32x4 h1 = {0.f, 0.f, 0.f, 0.f};
    h1 = __builtin_amdgcn_mfma_f32_16x16x32_bf16(a0, b0,  h1, 0, 0, 0);
    h1 = __builtin_amdgcn_mfma_f32_16x16x32_bf16(a1, b1f, h1, 0, 0, 0);

    // ---- bn2+relu; store hbn (D layout rows j=quad*4+r, col m) ----
    u16* myH = hbnT[wid];
#pragma unroll
    for (int r = 0; r < 4; ++r) {
        float hb = fmaxf(0.f, (h1[r] + wb1m) * s2 + bb2v);
        myH[(quad * 4 + r) * 16 + m] = f2b(hb);   // cols 8..15 dup -> same addr, same value
    }
    asm volatile("s_waitcnt lgkmcnt(0)" ::: "memory");
    __builtin_amdgcn_sched_barrier(0);

    // ---- h2 MFMA: A2[j][k=mm] nonzero only quad 0 ----
    bf16x8 a2 = {};
    if (quad == 0) a2 = *(const bf16x8*)&myH[n16 * 16];
    f32x4 scd = {0.f, 0.f, 0.f, 0.f};
    scd = __builtin_amdgcn_mfma_f32_16x16x32_bf16(a2, b2f_, scd, 0, 0, 0);

    // ---- softmax over j (4 regs x 4 quads) ----
    float e[4];
    float mx = -1e30f;
#pragma unroll
    for (int r = 0; r < 4; ++r) { e[r] = scd[r] + wb2m; mx = fmaxf(mx, e[r]); }
    mx = fmaxf(mx, __shfl_xor(mx, 16, 64));
    mx = fmaxf(mx, __shfl_xor(mx, 32, 64));
    float s = 0.f;
#pragma unroll
    for (int r = 0; r < 4; ++r) { e[r] = __expf(e[r] - mx); s += e[r]; }
    s += __shfl_xor(s, 16, 64);
    s += __shfl_xor(s, 32, 64);
    float rs = 1.f / s;
    float* myW = wT[wid];
#pragma unroll
    for (int r = 0; r < 4; ++r) myW[(quad * 4 + r) * 9 + m] = e[r] * rs;
    asm volatile("s_waitcnt lgkmcnt(0)" ::: "memory");
    __builtin_amdgcn_sched_barrier(0);

    // ---- weighted accumulate (vpr in regs, w via broadcast reads) ----
    float acc = 0.f;
#pragma unroll
    for (int j = 0; j < 16; ++j) acc += myW[j * 9 + m] * vpr[j];
    if (active) out[(size_t)i * 64 + lane] = acc;
}

// ---------------- fallback (ws too small): R10-proven recompute path ----------------
__global__ __launch_bounds__(256) void attn_fallback(
    const float* __restrict__ p, const int* __restrict__ idx32,
    const float* __restrict__ x,
    const float* __restrict__ Wq, const float* __restrict__ bq,
    const float* __restrict__ Wk, const float* __restrict__ bk,
    const float* __restrict__ Wv, const float* __restrict__ bv,
    const float* __restrict__ pw1, const float* __restrict__ pb1,
    const float* __restrict__ g3, const float* __restrict__ b3,
    const float* __restrict__ m3, const float* __restrict__ v3,
    const float* __restrict__ pw2, const float* __restrict__ pb2,
    const float* __restrict__ g1, const float* __restrict__ b1,
    const float* __restrict__ m1, const float* __restrict__ v1,
    const float* __restrict__ ww1, const float* __restrict__ wb1,
    const float* __restrict__ g2, const float* __restrict__ b2c,
    const float* __restrict__ m2, const float* __restrict__ v2,
    const float* __restrict__ ww2, const float* __restrict__ wb2,
    float* __restrict__ out, int N)
{
    const int lane = threadIdx.x & 63;
    const int wid  = threadIdx.x >> 6;
    int i = blockIdx.x * 4 + wid;
    bool active = (i < N);
    int ic = active ? i : 0;
    const int m = lane & 7;
    const int g = lane >> 3;
    bool idx64 = (idx32[1] == 0) & (idx32[3] == 0) & (idx32[5] == 0) & (idx32[7] == 0);

    float xi = x[(size_t)ic * 64 + lane];
    float qc = bq[lane];
#pragma unroll
    for (int kk = 0; kk < 64; ++kk)
        qc += __shfl(xi, kk, 64) * Wq[(size_t)lane * 64 + kk];
    float wkr[64], wvr[64];
#pragma unroll
    for (int tt = 0; tt < 64; ++tt) {
        wkr[tt] = Wk[(size_t)lane * 64 + tt];
        wvr[tt] = Wv[(size_t)lane * 64 + tt];
    }
    float bkc = bk[lane], bvc = bv[lane];
    float s1  = g1[lane] * rsqrtf(v1[lane] + EPSV);
    float bb1 = b1[lane] - m1[lane] * s1;
    float pw2_0 = pw2[lane * 3 + 0], pw2_1 = pw2[lane * 3 + 1], pw2_2 = pw2[lane * 3 + 2];
    float pb2c  = pb2[lane];
    float w1s[8];
#pragma unroll
    for (int tt = 0; tt < 8; ++tt) w1s[tt] = ww1[m * 64 + g * 8 + tt];
    float w2s[8];
#pragma unroll
    for (int tt = 0; tt < 8; ++tt) w2s[tt] = ww2[m * 8 + tt];
    float wb1m = wb1[m];
    float s2   = g2[m] * rsqrtf(v2[m] + EPSV);
    float bb2  = b2c[m] - m2[m] * s2;
    float wb2m = wb2[m];
    float pix = p[(size_t)ic * 3 + 0], piy = p[(size_t)ic * 3 + 1], piz = p[(size_t)ic * 3 + 2];
    size_t ii = (size_t)ic * 16 + (lane & 15);
    int nbr = idx64 ? idx32[ii * 2] : idx32[ii];
    if ((unsigned)nbr >= (unsigned)N) nbr = 0;
    float u0l, u1l, u2l;
    {
        float pdx = p[(size_t)nbr * 3 + 0] - pix;
        float pdy = p[(size_t)nbr * 3 + 1] - piy;
        float pdz = p[(size_t)nbr * 3 + 2] - piz;
        float a0 = pw1[0] * pdx + pw1[1] * pdy + pw1[2] * pdz + pb1[0];
        float a1 = pw1[3] * pdx + pw1[4] * pdy + pw1[5] * pdz + pb1[1];
        float a2 = pw1[6] * pdx + pw1[7] * pdy + pw1[8] * pdz + pb1[2];
        float sa0 = g3[0] * rsqrtf(v3[0] + EPSV);
        float sa1 = g3[1] * rsqrtf(v3[1] + EPSV);
        float sa2 = g3[2] * rsqrtf(v3[2] + EPSV);
        u0l = fmaxf(0.f, a0 * sa0 + (b3[0] - m3[0] * sa0));
        u1l = fmaxf(0.f, a1 * sa1 + (b3[1] - m3[1] * sa1));
        u2l = fmaxf(0.f, a2 * sa2 + (b3[2] - m3[2] * sa2));
    }
    float sc[16], vpr[16];
#pragma unroll
    for (int j = 0; j < 16; ++j) {
        int nj = __shfl(nbr, j, 64);
        float u0 = __shfl(u0l, j, 64);
        float u1 = __shfl(u1l, j, 64);
        float u2 = __shfl(u2l, j, 64);
        float pr = u0 * pw2_0 + u1 * pw2_1 + u2 * pw2_2 + pb2c;
        float xn = x[(size_t)nj * 64 + lane];
        float kc = bkc, vc = bvc;
#pragma unroll
        for (int kk = 0; kk < 64; ++kk) {
            float xk = __shfl(xn, kk, 64);
            kc += xk * wkr[kk];
            vc += xk * wvr[kk];
        }
        vpr[j] = vc + pr;
        float wr = fmaxf(0.f, (kc - qc + pr) * s1 + bb1);
        float partial = 0.f;
#pragma unroll
        for (int tt = 0; tt < 8; ++tt)
            partial += __shfl(wr, g * 8 + tt, 64) * w1s[tt];
        partial += __shfl_xor(partial, 8, 64);
        partial += __shfl_xor(partial, 16, 64);
        partial += __shfl_xor(partial, 32, 64);
        float hbn = fmaxf(0.f, (partial + wb1m) * s2 + bb2);
        float h2 = wb2m;
#pragma unroll
        for (int mm = 0; mm < 8; ++mm)
            h2 += __shfl(hbn, (lane & 56) | mm, 64) * w2s[mm];
        sc[j] = h2;
    }
    float mx = sc[0];
#pragma unroll
    for (int j = 1; j < 16; ++j) mx = fmaxf(mx, sc[j]);
    float sum = 0.f, acc = 0.f;
#pragma unroll
    for (int j = 0; j < 16; ++j) {
        float e = __expf(sc[j] - mx);
        sum += e;
        acc += e * vpr[j];
    }
    if (active) out[(size_t)i * 64 + lane] = acc / sum;
}

// ---------------- launch ----------------
extern "C" void kernel_launch(void* const* d_in, const int* in_sizes, int n_in,
                              void* d_out, int out_size, void* d_ws, size_t ws_size,
                              hipStream_t stream) {
    const float* p   = (const float*)d_in[0];
    const float* x   = (const float*)d_in[1];
    const int* idx   = (const int*)d_in[2];
    const float* Wq  = (const float*)d_in[3];
    const float* bq  = (const float*)d_in[4];
    const float* Wk  = (const float*)d_in[5];
    const float* bk  = (const float*)d_in[6];
    const float* Wv  = (const float*)d_in[7];
    const float* bv  = (const float*)d_in[8];
    const float* pw1 = (const float*)d_in[9];
    const float* pb1 = (const float*)d_in[10];
    const float* g3  = (const float*)d_in[11];
    const float* b3  = (const float*)d_in[12];
    const float* m3  = (const float*)d_in[13];
    const float* v3  = (const float*)d_in[14];
    const float* pw2 = (const float*)d_in[15];
    const float* pb2 = (const float*)d_in[16];
    const float* g1  = (const float*)d_in[17];
    const float* b1  = (const float*)d_in[18];
    const float* m1  = (const float*)d_in[19];
    const float* v1  = (const float*)d_in[20];
    const float* ww1 = (const float*)d_in[21];
    const float* wb1 = (const float*)d_in[22];
    const float* g2  = (const float*)d_in[23];
    const float* b2  = (const float*)d_in[24];
    const float* m2  = (const float*)d_in[25];
    const float* v2  = (const float*)d_in[26];
    const float* ww2 = (const float*)d_in[27];
    const float* wb2 = (const float*)d_in[28];

    int N = in_sizes[0] / 3;
    size_t plane = (size_t)N * 64;
    bool tier1 = ws_size >= plane * 2 + plane * 4;   // qb u16 + kvb u32 = 38.4 MB

    u16* qb  = (u16*)d_ws;
    u32* kvb = (u32*)(qb + plane);

    int blocks = (N + 3) / 4;
    float* out = (float*)d_out;

    if (tier1) {
        int gblocks = (N + 63) / 64;
        kvq_mfma<<<gblocks, 256, 0, stream>>>(x, Wq, bq, Wk, bk, Wv, bv, qb, kvb, N);
        attn_mfma<<<blocks, 256, 0, stream>>>(p, idx, qb, kvb,
            pw1, pb1, g3, b3, m3, v3, pw2, pb2, g1, b1, m1, v1, ww1, wb1,
            g2, b2, m2, v2, ww2, wb2, out, N);
    } else {
        attn_fallback<<<blocks, 256, 0, stream>>>(p, idx, x, Wq, bq, Wk, bk, Wv, bv,
            pw1, pb1, g3, b3, m3, v3, pw2, pb2, g1, b1, m1, v1, ww1, wb1,
            g2, b2, m2, v2, ww2, wb2, out, N);
    }
}

// Round 2
// 210.008 us; speedup vs baseline: 1.2458x; 1.1430x over previous
//
#include <hip/hip_runtime.h>
#include <hip/hip_bf16.h>

typedef unsigned short u16;
typedef unsigned int   u32;
typedef __attribute__((ext_vector_type(8))) short bf16x8;
typedef __attribute__((ext_vector_type(4))) float f32x4;

#define EPSV 1e-5f

// Established (R1-R11): all float inputs fp32, idx int32-or-int64, output fp32.
// ws planes bf16/u32-packed (absmax 0.0078 << 0.0273 threshold).
// R11: wave-private LDS -> lgkmcnt-only sync (no __syncthreads), readlane
// broadcasts, batched scalar-base kv gathers. 132 -> 113 us.
// R12: hoist ALL constant conversion/folding out of attn (ws param tail filled
// by kvq block 0), v_cvt_pk_bf16_f32 for runtime bf16 packs, drop wb2m
// (cancels in softmax), fold qc into bias. Attacks VALUBusy=85%.
__device__ __forceinline__ float b2f(u16 u) {
    union { u32 i; float f; } x; x.i = ((u32)u) << 16; return x.f;
}
__device__ __forceinline__ u16 f2b(float f) {
    union { float f; u32 i; } x; x.f = f;
    u32 lsb = (x.i >> 16) & 1u;
    return (u16)((x.i + 0x7fffu + lsb) >> 16);
}
__device__ __forceinline__ float rdlane_f(float v, int lane) {
    return __uint_as_float(__builtin_amdgcn_readlane(__float_as_uint(v), lane));
}
__device__ __forceinline__ u32 cvtpk_bf16(float lo, float hi) {
    u32 r;
    asm("v_cvt_pk_bf16_f32 %0, %1, %2" : "=v"(r) : "v"(lo), "v"(hi));
    return r;
}

// ws tail layout (byte offsets from plane*6):
//   +0    chanP4[64]  float4 {pw2_0, pw2_1, pw2_2, pb2}
//   +1024 chanP2[64]  float2 {s1, bb1}
//   +1536 mP[8]       float4 {s2, bb2 + wb1*s2, 0, 0}
//   +1664 pP[12]      float  {P00..P22 (sa-folded pw1), Q0..Q2}
//   +1792 wwb1[512]   u16    bf16(ww1) row-major 8x64
//   +2816 wwb2[64]    u16    bf16(ww2) row-major 8x8
//   end   +2944  (tier1 check uses +3072)

// ---------------- Kernel 1: q/k/v projection + param prep ----------------
__global__ __launch_bounds__(256) void kvq_mfma(
    const float* __restrict__ x,
    const float* __restrict__ Wq, const float* __restrict__ bq,
    const float* __restrict__ Wk, const float* __restrict__ bk,
    const float* __restrict__ Wv, const float* __restrict__ bv,
    u16* __restrict__ qb, u32* __restrict__ kvb,
    const float* __restrict__ g1, const float* __restrict__ b1,
    const float* __restrict__ m1, const float* __restrict__ v1,
    const float* __restrict__ pw2, const float* __restrict__ pb2,
    const float* __restrict__ g2, const float* __restrict__ b2c,
    const float* __restrict__ m2, const float* __restrict__ v2,
    const float* __restrict__ wb1,
    const float* __restrict__ pw1, const float* __restrict__ pb1,
    const float* __restrict__ g3, const float* __restrict__ b3,
    const float* __restrict__ m3, const float* __restrict__ v3,
    const float* __restrict__ ww1, const float* __restrict__ ww2,
    float4* __restrict__ chanP4, float2* __restrict__ chanP2,
    float4* __restrict__ mP, float* __restrict__ pP,
    u16* __restrict__ wwb1, u16* __restrict__ wwb2,
    int N)
{
    __shared__ u16 Wl[3 * 64 * 72];
    __shared__ u16 xl[64 * 72];
    const int t = threadIdx.x;

    const float* Wg[3] = {Wq, Wk, Wv};
#pragma unroll
    for (int mat = 0; mat < 3; ++mat) {
        const float4* Wsrc = (const float4*)Wg[mat];
#pragma unroll
        for (int it = 0; it < 4; ++it) {
            int id4 = t + it * 256;
            int row = id4 >> 4;
            int c4  = id4 & 15;
            float4 f = Wsrc[id4];
            u32 lo = (u32)f2b(f.x) | ((u32)f2b(f.y) << 16);
            u32 hi = (u32)f2b(f.z) | ((u32)f2b(f.w) << 16);
            u32* d = (u32*)&Wl[(mat * 64 + row) * 72 + c4 * 4];
            d[0] = lo; d[1] = hi;
        }
    }
    int base = blockIdx.x * 64;
#pragma unroll
    for (int it = 0; it < 4; ++it) {
        int id4 = t + it * 256;
        int row = id4 >> 4;
        int c4  = id4 & 15;
        int gi = base + row; if (gi >= N) gi = N - 1;
        float4 f = ((const float4*)(x + (size_t)gi * 64))[c4];
        u32 lo = (u32)f2b(f.x) | ((u32)f2b(f.y) << 16);
        u32 hi = (u32)f2b(f.z) | ((u32)f2b(f.w) << 16);
        u32* d = (u32*)&xl[row * 72 + c4 * 4];
        d[0] = lo; d[1] = hi;
    }
    __syncthreads();

    const int lane = t & 63;
    const int wid  = t >> 6;
    const int n_   = lane & 15;
    const int quad = lane >> 4;

    bf16x8 a0 = *(const bf16x8*)&xl[(wid * 16 + n_) * 72 + quad * 8];
    bf16x8 a1 = *(const bf16x8*)&xl[(wid * 16 + n_) * 72 + 32 + quad * 8];

    f32x4 acc[12];
#pragma unroll
    for (int nt = 0; nt < 12; ++nt) {
        int mat = nt >> 2;
        int c = ((nt & 3) << 4) + n_;
        bf16x8 b0 = *(const bf16x8*)&Wl[(mat * 64 + c) * 72 + quad * 8];
        bf16x8 b1 = *(const bf16x8*)&Wl[(mat * 64 + c) * 72 + 32 + quad * 8];
        f32x4 z = {0.f, 0.f, 0.f, 0.f};
        z = __builtin_amdgcn_mfma_f32_16x16x32_bf16(a0, b0, z, 0, 0, 0);
        z = __builtin_amdgcn_mfma_f32_16x16x32_bf16(a1, b1, z, 0, 0, 0);
        acc[nt] = z;
    }

    int rbase = base + wid * 16 + quad * 4;
#pragma unroll
    for (int g4 = 0; g4 < 4; ++g4) {
        int c = (g4 << 4) + n_;
        float biasq = bq[c], biask = bk[c], biasv = bv[c];
#pragma unroll
        for (int r = 0; r < 4; ++r) {
            int i2 = rbase + r;
            if (i2 < N) {
                qb[(size_t)i2 * 64 + c] = f2b(acc[g4][r] + biasq);
                u32 kvp = (u32)f2b(acc[4 + g4][r] + biask)
                        | ((u32)f2b(acc[8 + g4][r] + biasv) << 16);
                kvb[(size_t)i2 * 64 + c] = kvp;
            }
        }
    }

    // ---- param prep (block 0 only; visible to attn_mfma at kernel boundary) ----
    if (blockIdx.x == 0) {
        if (t < 64) {
            float s1 = g1[t] * rsqrtf(v1[t] + EPSV);
            float bb1 = b1[t] - m1[t] * s1;
            chanP4[t] = make_float4(pw2[t * 3 + 0], pw2[t * 3 + 1], pw2[t * 3 + 2], pb2[t]);
            chanP2[t] = make_float2(s1, bb1);
            wwb2[t] = f2b(ww2[t]);
        }
        if (t < 8) {
            float s2 = g2[t] * rsqrtf(v2[t] + EPSV);
            float bb2f = b2c[t] - m2[t] * s2 + wb1[t] * s2;
            mP[t] = make_float4(s2, bb2f, 0.f, 0.f);
        }
        if (t < 9) {
            int r = t / 3;
            float sa = g3[r] * rsqrtf(v3[r] + EPSV);
            pP[t] = sa * pw1[t];
        }
        if (t >= 9 && t < 12) {
            int r = t - 9;
            float sa = g3[r] * rsqrtf(v3[r] + EPSV);
            pP[t] = sa * (pb1[r] - m3[r]) + b3[r];
        }
        wwb1[t]       = f2b(ww1[t]);
        wwb1[t + 256] = f2b(ww1[t + 256]);
    }
}

// ---------------- Kernel 2: fused attention, MFMA score path ----------------
__global__ __launch_bounds__(256) void attn_mfma(
    const float* __restrict__ p, const int* __restrict__ idx32,
    const u16* __restrict__ qb, const u32* __restrict__ kvb,
    const float4* __restrict__ chanP4, const float2* __restrict__ chanP2,
    const float4* __restrict__ mP, const float* __restrict__ pP,
    const u16* __restrict__ wwb1, const u16* __restrict__ wwb2,
    float* __restrict__ out, int N)
{
    __shared__ u16   wrT[4][16 * 72];   // wr transpose, row stride 72 u16
    __shared__ u16   hbnT[4][16 * 16];  // hbn transpose, row stride 16 u16
    __shared__ float wT[4][16 * 9];     // softmax weights, row stride 9 f32

    const int lane = threadIdx.x & 63;
    const int wid  = threadIdx.x >> 6;
    int i = blockIdx.x * 4 + wid;
    bool active = (i < N);
    int ic = active ? i : 0;
    const int m    = lane & 7;
    const int n16  = lane & 15;
    const int quad = lane >> 4;

    bool idx64 = (idx32[1] == 0) & (idx32[3] == 0) & (idx32[5] == 0) & (idx32[7] == 0);

    // ---- prefolded per-lane params ----
    float4 cp = chanP4[lane];           // pw2_0..2, pb2
    float2 sp = chanP2[lane];           // s1, bb1
    float4 mp = mP[m];                  // s2, bb2+wb1*s2
    float qc  = b2f(qb[(size_t)ic * 64 + lane]);
    float s1  = sp.x;
    float bb1q = sp.y - qc * s1;        // fold q into bias
    float pix = p[(size_t)ic * 3 + 0];
    float piy = p[(size_t)ic * 3 + 1];
    float piz = p[(size_t)ic * 3 + 2];

    // neighbor index for this lane's slot
    size_t ii = (size_t)ic * 16 + n16;
    int nbr = idx64 ? idx32[ii * 2] : idx32[ii];
    if ((unsigned)nbr >= (unsigned)N) nbr = 0;

    // ---- linear_p u-values once in lane j (sa prefolded into pP) ----
    float u0l, u1l, u2l;
    {
        float pdx = p[(size_t)nbr * 3 + 0] - pix;
        float pdy = p[(size_t)nbr * 3 + 1] - piy;
        float pdz = p[(size_t)nbr * 3 + 2] - piz;
        u0l = fmaxf(0.f, fmaf(pP[0], pdx, fmaf(pP[1], pdy, fmaf(pP[2], pdz, pP[9]))));
        u1l = fmaxf(0.f, fmaf(pP[3], pdx, fmaf(pP[4], pdy, fmaf(pP[5], pdz, pP[10]))));
        u2l = fmaxf(0.f, fmaf(pP[6], pdx, fmaf(pP[7], pdy, fmaf(pP[8], pdz, pP[11]))));
    }

    // ---- B fragments: direct bf16 loads (pre-converted, zero VALU) ----
    bf16x8 b0  = *(const bf16x8*)&wwb1[(size_t)m * 64 + quad * 8];
    bf16x8 b1f = *(const bf16x8*)&wwb1[(size_t)m * 64 + 32 + quad * 8];
    bf16x8 b2f_ = {};
    if (quad == 0) b2f_ = *(const bf16x8*)&wwb2[(size_t)m * 8];

    // ---- batch the 16 kv gathers (scalar base addresses, all in flight) ----
    u32 kvw[16];
#pragma unroll
    for (int j = 0; j < 16; ++j) {
        int nj = __builtin_amdgcn_readlane(nbr, j);
        kvw[j] = kvb[(size_t)nj * 64 + lane];
    }

    // ---- per-neighbor-pair: pr, wr -> LDS (A-transpose), vpr in regs ----
    float vpr[16];
    u16* myWr = wrT[wid];
#pragma unroll
    for (int jp = 0; jp < 8; ++jp) {
        const int j0 = 2 * jp, j1 = j0 + 1;
        float pr0 = fmaf(rdlane_f(u0l, j0), cp.x,
                    fmaf(rdlane_f(u1l, j0), cp.y,
                    fmaf(rdlane_f(u2l, j0), cp.z, cp.w)));
        float pr1 = fmaf(rdlane_f(u0l, j1), cp.x,
                    fmaf(rdlane_f(u1l, j1), cp.y,
                    fmaf(rdlane_f(u2l, j1), cp.z, cp.w)));
        u32 w0 = kvw[j0], w1 = kvw[j1];
        float kc0 = __uint_as_float(w0 << 16);
        float vc0 = __uint_as_float(w0 & 0xffff0000u);
        float kc1 = __uint_as_float(w1 << 16);
        float vc1 = __uint_as_float(w1 & 0xffff0000u);
        vpr[j0] = vc0 + pr0;
        vpr[j1] = vc1 + pr1;
        float wr0 = fmaxf(0.f, fmaf(kc0 + pr0, s1, bb1q));
        float wr1 = fmaxf(0.f, fmaf(kc1 + pr1, s1, bb1q));
        u32 pk = cvtpk_bf16(wr0, wr1);
        myWr[j0 * 72 + lane] = (u16)pk;
        myWr[j1 * 72 + lane] = (u16)(pk >> 16);
    }
    // same-wave LDS RAW only -> lgkmcnt drain, no block barrier
    asm volatile("s_waitcnt lgkmcnt(0)" ::: "memory");
    __builtin_amdgcn_sched_barrier(0);

    // ---- h1 MFMA: A row j=n16, k = quad*8.. / 32+quad*8.. ----
    bf16x8 a0 = *(const bf16x8*)&myWr[n16 * 72 + quad * 8];
    bf16x8 a1 = *(const bf16x8*)&myWr[n16 * 72 + 32 + quad * 8];
    f32x4 h1 = {0.f, 0.f, 0.f, 0.f};
    h1 = __builtin_amdgcn_mfma_f32_16x16x32_bf16(a0, b0,  h1, 0, 0, 0);
    h1 = __builtin_amdgcn_mfma_f32_16x16x32_bf16(a1, b1f, h1, 0, 0, 0);

    // ---- bn2+relu; store hbn (D layout rows j=quad*4+r, col m) ----
    u16* myH = hbnT[wid];
    {
        float hb0 = fmaxf(0.f, fmaf(h1[0], mp.x, mp.y));
        float hb1 = fmaxf(0.f, fmaf(h1[1], mp.x, mp.y));
        float hb2 = fmaxf(0.f, fmaf(h1[2], mp.x, mp.y));
        float hb3 = fmaxf(0.f, fmaf(h1[3], mp.x, mp.y));
        u32 pk01 = cvtpk_bf16(hb0, hb1);
        u32 pk23 = cvtpk_bf16(hb2, hb3);
        myH[(quad * 4 + 0) * 16 + m] = (u16)pk01;
        myH[(quad * 4 + 1) * 16 + m] = (u16)(pk01 >> 16);
        myH[(quad * 4 + 2) * 16 + m] = (u16)pk23;
        myH[(quad * 4 + 3) * 16 + m] = (u16)(pk23 >> 16);
    }
    asm volatile("s_waitcnt lgkmcnt(0)" ::: "memory");
    __builtin_amdgcn_sched_barrier(0);

    // ---- h2 MFMA: A2[j][k=mm] nonzero only quad 0 ----
    bf16x8 a2 = {};
    if (quad == 0) a2 = *(const bf16x8*)&myH[n16 * 16];
    f32x4 scd = {0.f, 0.f, 0.f, 0.f};
    scd = __builtin_amdgcn_mfma_f32_16x16x32_bf16(a2, b2f_, scd, 0, 0, 0);

    // ---- softmax over j (wb2m dropped: constant per column, cancels) ----
    float e[4];
    float mx = -1e30f;
#pragma unroll
    for (int r = 0; r < 4; ++r) { e[r] = scd[r]; mx = fmaxf(mx, e[r]); }
    mx = fmaxf(mx, __shfl_xor(mx, 16, 64));
    mx = fmaxf(mx, __shfl_xor(mx, 32, 64));
    float s = 0.f;
#pragma unroll
    for (int r = 0; r < 4; ++r) { e[r] = __expf(e[r] - mx); s += e[r]; }
    s += __shfl_xor(s, 16, 64);
    s += __shfl_xor(s, 32, 64);
    float rs = 1.f / s;
    float* myW = wT[wid];
#pragma unroll
    for (int r = 0; r < 4; ++r) myW[(quad * 4 + r) * 9 + m] = e[r] * rs;
    asm volatile("s_waitcnt lgkmcnt(0)" ::: "memory");
    __builtin_amdgcn_sched_barrier(0);

    // ---- weighted accumulate (vpr in regs, w via broadcast reads) ----
    float acc = 0.f;
#pragma unroll
    for (int j = 0; j < 16; ++j) acc += myW[j * 9 + m] * vpr[j];
    if (active) out[(size_t)i * 64 + lane] = acc;
}

// ---------------- fallback (ws too small): R10-proven recompute path ----------------
__global__ __launch_bounds__(256) void attn_fallback(
    const float* __restrict__ p, const int* __restrict__ idx32,
    const float* __restrict__ x,
    const float* __restrict__ Wq, const float* __restrict__ bq,
    const float* __restrict__ Wk, const float* __restrict__ bk,
    const float* __restrict__ Wv, const float* __restrict__ bv,
    const float* __restrict__ pw1, const float* __restrict__ pb1,
    const float* __restrict__ g3, const float* __restrict__ b3,
    const float* __restrict__ m3, const float* __restrict__ v3,
    const float* __restrict__ pw2, const float* __restrict__ pb2,
    const float* __restrict__ g1, const float* __restrict__ b1,
    const float* __restrict__ m1, const float* __restrict__ v1,
    const float* __restrict__ ww1, const float* __restrict__ wb1,
    const float* __restrict__ g2, const float* __restrict__ b2c,
    const float* __restrict__ m2, const float* __restrict__ v2,
    const float* __restrict__ ww2, const float* __restrict__ wb2,
    float* __restrict__ out, int N)
{
    const int lane = threadIdx.x & 63;
    const int wid  = threadIdx.x >> 6;
    int i = blockIdx.x * 4 + wid;
    bool active = (i < N);
    int ic = active ? i : 0;
    const int m = lane & 7;
    const int g = lane >> 3;
    bool idx64 = (idx32[1] == 0) & (idx32[3] == 0) & (idx32[5] == 0) & (idx32[7] == 0);

    float xi = x[(size_t)ic * 64 + lane];
    float qc = bq[lane];
#pragma unroll
    for (int kk = 0; kk < 64; ++kk)
        qc += __shfl(xi, kk, 64) * Wq[(size_t)lane * 64 + kk];
    float wkr[64], wvr[64];
#pragma unroll
    for (int tt = 0; tt < 64; ++tt) {
        wkr[tt] = Wk[(size_t)lane * 64 + tt];
        wvr[tt] = Wv[(size_t)lane * 64 + tt];
    }
    float bkc = bk[lane], bvc = bv[lane];
    float s1  = g1[lane] * rsqrtf(v1[lane] + EPSV);
    float bb1 = b1[lane] - m1[lane] * s1;
    float pw2_0 = pw2[lane * 3 + 0], pw2_1 = pw2[lane * 3 + 1], pw2_2 = pw2[lane * 3 + 2];
    float pb2c  = pb2[lane];
    float w1s[8];
#pragma unroll
    for (int tt = 0; tt < 8; ++tt) w1s[tt] = ww1[m * 64 + g * 8 + tt];
    float w2s[8];
#pragma unroll
    for (int tt = 0; tt < 8; ++tt) w2s[tt] = ww2[m * 8 + tt];
    float wb1m = wb1[m];
    float s2   = g2[m] * rsqrtf(v2[m] + EPSV);
    float bb2  = b2c[m] - m2[m] * s2;
    float wb2m = wb2[m];
    float pix = p[(size_t)ic * 3 + 0], piy = p[(size_t)ic * 3 + 1], piz = p[(size_t)ic * 3 + 2];
    size_t ii = (size_t)ic * 16 + (lane & 15);
    int nbr = idx64 ? idx32[ii * 2] : idx32[ii];
    if ((unsigned)nbr >= (unsigned)N) nbr = 0;
    float u0l, u1l, u2l;
    {
        float pdx = p[(size_t)nbr * 3 + 0] - pix;
        float pdy = p[(size_t)nbr * 3 + 1] - piy;
        float pdz = p[(size_t)nbr * 3 + 2] - piz;
        float a0 = pw1[0] * pdx + pw1[1] * pdy + pw1[2] * pdz + pb1[0];
        float a1 = pw1[3] * pdx + pw1[4] * pdy + pw1[5] * pdz + pb1[1];
        float a2 = pw1[6] * pdx + pw1[7] * pdy + pw1[8] * pdz + pb1[2];
        float sa0 = g3[0] * rsqrtf(v3[0] + EPSV);
        float sa1 = g3[1] * rsqrtf(v3[1] + EPSV);
        float sa2 = g3[2] * rsqrtf(v3[2] + EPSV);
        u0l = fmaxf(0.f, a0 * sa0 + (b3[0] - m3[0] * sa0));
        u1l = fmaxf(0.f, a1 * sa1 + (b3[1] - m3[1] * sa1));
        u2l = fmaxf(0.f, a2 * sa2 + (b3[2] - m3[2] * sa2));
    }
    float sc[16], vpr[16];
#pragma unroll
    for (int j = 0; j < 16; ++j) {
        int nj = __shfl(nbr, j, 64);
        float u0 = __shfl(u0l, j, 64);
        float u1 = __shfl(u1l, j, 64);
        float u2 = __shfl(u2l, j, 64);
        float pr = u0 * pw2_0 + u1 * pw2_1 + u2 * pw2_2 + pb2c;
        float xn = x[(size_t)nj * 64 + lane];
        float kc = bkc, vc = bvc;
#pragma unroll
        for (int kk = 0; kk < 64; ++kk) {
            float xk = __shfl(xn, kk, 64);
            kc += xk * wkr[kk];
            vc += xk * wvr[kk];
        }
        vpr[j] = vc + pr;
        float wr = fmaxf(0.f, (kc - qc + pr) * s1 + bb1);
        float partial = 0.f;
#pragma unroll
        for (int tt = 0; tt < 8; ++tt)
            partial += __shfl(wr, g * 8 + tt, 64) * w1s[tt];
        partial += __shfl_xor(partial, 8, 64);
        partial += __shfl_xor(partial, 16, 64);
        partial += __shfl_xor(partial, 32, 64);
        float hbn = fmaxf(0.f, (partial + wb1m) * s2 + bb2);
        float h2 = wb2m;
#pragma unroll
        for (int mm = 0; mm < 8; ++mm)
            h2 += __shfl(hbn, (lane & 56) | mm, 64) * w2s[mm];
        sc[j] = h2;
    }
    float mx = sc[0];
#pragma unroll
    for (int j = 1; j < 16; ++j) mx = fmaxf(mx, sc[j]);
    float sum = 0.f, acc = 0.f;
#pragma unroll
    for (int j = 0; j < 16; ++j) {
        float e = __expf(sc[j] - mx);
        sum += e;
        acc += e * vpr[j];
    }
    if (active) out[(size_t)i * 64 + lane] = acc / sum;
}

// ---------------- launch ----------------
extern "C" void kernel_launch(void* const* d_in, const int* in_sizes, int n_in,
                              void* d_out, int out_size, void* d_ws, size_t ws_size,
                              hipStream_t stream) {
    const float* p   = (const float*)d_in[0];
    const float* x   = (const float*)d_in[1];
    const int* idx   = (const int*)d_in[2];
    const float* Wq  = (const float*)d_in[3];
    const float* bq  = (const float*)d_in[4];
    const float* Wk  = (const float*)d_in[5];
    const float* bk  = (const float*)d_in[6];
    const float* Wv  = (const float*)d_in[7];
    const float* bv  = (const float*)d_in[8];
    const float* pw1 = (const float*)d_in[9];
    const float* pb1 = (const float*)d_in[10];
    const float* g3  = (const float*)d_in[11];
    const float* b3  = (const float*)d_in[12];
    const float* m3  = (const float*)d_in[13];
    const float* v3  = (const float*)d_in[14];
    const float* pw2 = (const float*)d_in[15];
    const float* pb2 = (const float*)d_in[16];
    const float* g1  = (const float*)d_in[17];
    const float* b1  = (const float*)d_in[18];
    const float* m1  = (const float*)d_in[19];
    const float* v1  = (const float*)d_in[20];
    const float* ww1 = (const float*)d_in[21];
    const float* wb1 = (const float*)d_in[22];
    const float* g2  = (const float*)d_in[23];
    const float* b2  = (const float*)d_in[24];
    const float* m2  = (const float*)d_in[25];
    const float* v2  = (const float*)d_in[26];
    const float* ww2 = (const float*)d_in[27];
    const float* wb2 = (const float*)d_in[28];

    int N = in_sizes[0] / 3;
    size_t plane = (size_t)N * 64;
    bool tier1 = ws_size >= plane * 6 + 3072;   // qb u16 + kvb u32 + 3KB param tail

    u16* qb  = (u16*)d_ws;
    u32* kvb = (u32*)(qb + plane);
    char* extra = (char*)d_ws + plane * 6;
    float4* chanP4 = (float4*)(extra);
    float2* chanP2 = (float2*)(extra + 1024);
    float4* mP     = (float4*)(extra + 1536);
    float*  pP     = (float*)(extra + 1664);
    u16*    wwb1   = (u16*)(extra + 1792);
    u16*    wwb2   = (u16*)(extra + 2816);

    int blocks = (N + 3) / 4;
    float* out = (float*)d_out;

    if (tier1) {
        int gblocks = (N + 63) / 64;
        kvq_mfma<<<gblocks, 256, 0, stream>>>(x, Wq, bq, Wk, bk, Wv, bv, qb, kvb,
            g1, b1, m1, v1, pw2, pb2, g2, b2, m2, v2, wb1,
            pw1, pb1, g3, b3, m3, v3, ww1, ww2,
            chanP4, chanP2, mP, pP, wwb1, wwb2, N);
        attn_mfma<<<blocks, 256, 0, stream>>>(p, idx, qb, kvb,
            chanP4, chanP2, mP, pP, wwb1, wwb2, out, N);
    } else {
        attn_fallback<<<blocks, 256, 0, stream>>>(p, idx, x, Wq, bq, Wk, bk, Wv, bv,
            pw1, pb1, g3, b3, m3, v3, pw2, pb2, g1, b1, m1, v1, ww1, wb1,
            g2, b2, m2, v2, ww2, wb2, out, N);
    }
}